// Round 1
// baseline (989.780 us; speedup 1.0000x reference)
//
#include <hip/hip_runtime.h>
#include <cstdint>

#define NTOK  49
#define NHEAD 16
#define HD    32
#define BATCH 2048
#define MTOT  (BATCH*NTOK)                 // 100352
#define SCALE 0.17677669529663687f        // 1/sqrt(32)

typedef float  f32x4  __attribute__((ext_vector_type(4)));
typedef __bf16 bf16x8 __attribute__((ext_vector_type(8)));
typedef unsigned int u32;
typedef const u32 __attribute__((address_space(1)))* gas_u32p;
typedef u32 __attribute__((address_space(3)))* las_u32p;

__device__ __forceinline__ void gld16(__bf16* lds, const __bf16* g) {
    __builtin_amdgcn_global_load_lds((gas_u32p)(const void*)g, (las_u32p)(void*)lds, 16, 0, 0);
}

// ---------------- prep kernels ----------------

__global__ __launch_bounds__(256) void cvt_x(const float* __restrict__ x,
                                             __bf16* __restrict__ o, long n) {
    long i = ((long)blockIdx.x * 256 + threadIdx.x) * 8;
    if (i >= n) return;
    float4 a = *(const float4*)(x + i);
    float4 b = *(const float4*)(x + i + 4);
    bf16x8 t;
    t[0] = (__bf16)a.x; t[1] = (__bf16)a.y; t[2] = (__bf16)a.z; t[3] = (__bf16)a.w;
    t[4] = (__bf16)b.x; t[5] = (__bf16)b.y; t[6] = (__bf16)b.z; t[7] = (__bf16)b.w;
    *(bf16x8*)(o + i) = t;
}

// transpose qkv_w [512,1536] -> [1536,512] bf16 (scale q rows), proj_w [512,512] -> [512,512]^T,
// and scaled qkv bias
__global__ __launch_bounds__(256) void prep_w(const float* __restrict__ qkv_w,
                                              const float* __restrict__ proj_w,
                                              const float* __restrict__ qkv_b,
                                              __bf16* __restrict__ wqkv_t,
                                              __bf16* __restrict__ wp_t,
                                              float* __restrict__ qkvb_s) {
    int idx = blockIdx.x * 256 + threadIdx.x;
    if (idx < 1536 * 512) {
        int nn = idx >> 9, kk = idx & 511;
        float v = qkv_w[kk * 1536 + nn];
        if (nn < 512) v *= SCALE;
        wqkv_t[idx] = (__bf16)v;
    } else if (idx < 1536 * 512 + 512 * 512) {
        int j = idx - 1536 * 512;
        int nn = j >> 9, kk = j & 511;
        wp_t[j] = (__bf16)proj_w[kk * 512 + nn];
    } else if (idx < 1536 * 512 + 512 * 512 + 1536) {
        int n = idx - (1536 * 512 + 512 * 512);
        float v = qkv_b[n];
        if (n < 512) v *= SCALE;
        qkvb_s[n] = v;
    }
}

// addm[h][w][j][i_pad64] = rel_bias[h][i][j] + mask[w][i][j];  j>=49 -> -1e30 ; i>=49 -> 0
__global__ __launch_bounds__(256) void prep_addm(const float* __restrict__ mask,
                                                 const float* __restrict__ bias_table,
                                                 float* __restrict__ addm) {
    int idx = blockIdx.x * 256 + threadIdx.x;           // 16*64*64*64 = 4194304 exact
    int i = idx & 63, j = (idx >> 6) & 63, w = (idx >> 12) & 63, h = idx >> 18;
    float v;
    if (j >= 49)      v = -1e30f;
    else if (i >= 49) v = 0.f;
    else {
        int ai = (i * 37) >> 8, aj = i - ai * 7;
        int bi = (j * 37) >> 8, bj = j - bi * 7;
        int ridx = (ai - bi + 6) * 13 + (aj - bj + 6);
        v = bias_table[ridx * 16 + h] + mask[(w * 49 + i) * 49 + j];
    }
    addm[idx] = v;
}

// ---------------- GEMM (M x 512) * (512 x N) with Bt[N,512], 128x128 tile ----------------

template <int OUT_BF16>
__global__ __launch_bounds__(256)
void gemm_k512(const __bf16* __restrict__ A, const __bf16* __restrict__ Bt,
               const float* __restrict__ bias, void* __restrict__ Cout, int N) {
    __shared__ __bf16 a_sh[128 * 32];
    __shared__ __bf16 b_sh[128 * 32];
    const int tid = threadIdx.x;
    const int wid = tid >> 6;
    const int lane = tid & 63;
    const int g = lane >> 4, c = lane & 15;
    const int r = lane >> 2;             // staging row within 16-row chunk
    const int c8 = (lane & 3) * 8;       // staging col (8 bf16 = 16B)
    const long m0 = (long)blockIdx.y * 128;
    const long n0 = (long)blockIdx.x * 128;

    const __bf16* aA = A + (m0 + wid * 32 + r) * 512 + c8;
    const __bf16* aB = Bt + (n0 + wid * 32 + r) * 512 + c8;
    __bf16* lA = a_sh + wid * 32 * 32;
    __bf16* lB = b_sh + wid * 32 * 32;

    f32x4 acc[4][4];
    for (int i = 0; i < 4; ++i)
        for (int j = 0; j < 4; ++j) acc[i][j] = (f32x4){0.f, 0.f, 0.f, 0.f};

    const int wm = (wid >> 1) * 64;
    const int wn = (wid & 1) * 64;

    for (int kt = 0; kt < 16; ++kt) {
        const int ko = kt * 32;
        gld16(lA,           aA + ko);
        gld16(lA + 16 * 32, aA + (long)16 * 512 + ko);
        gld16(lB,           aB + ko);
        gld16(lB + 16 * 32, aB + (long)16 * 512 + ko);
        __syncthreads();
        bf16x8 af[4], bf[4];
        for (int mt = 0; mt < 4; ++mt)
            af[mt] = *(const bf16x8*)(a_sh + (wm + mt * 16 + c) * 32 + g * 8);
        for (int nt = 0; nt < 4; ++nt)
            bf[nt] = *(const bf16x8*)(b_sh + (wn + nt * 16 + c) * 32 + g * 8);
        for (int mt = 0; mt < 4; ++mt)
            for (int nt = 0; nt < 4; ++nt)
                acc[mt][nt] = __builtin_amdgcn_mfma_f32_16x16x32_bf16(af[mt], bf[nt], acc[mt][nt], 0, 0, 0);
        __syncthreads();
    }

    for (int nt = 0; nt < 4; ++nt) {
        const long n = n0 + wn + nt * 16 + c;
        const float bv = bias[n];
        for (int mt = 0; mt < 4; ++mt) {
            const long row0 = m0 + wm + mt * 16 + g * 4;
            for (int rr = 0; rr < 4; ++rr) {
                float v = acc[mt][nt][rr] + bv;
                if (OUT_BF16) ((__bf16*)Cout)[(row0 + rr) * (long)N + n] = (__bf16)v;
                else          ((float*)Cout)[(row0 + rr) * (long)N + n] = v;
            }
        }
    }
}

// ---------------- attention: one wave per (b,h) ----------------

__global__ __launch_bounds__(256)
void attn_k(const __bf16* __restrict__ qkv, const float* __restrict__ addm,
            __bf16* __restrict__ ao) {
    __shared__ float p_all[4][64 * 68];
    const int tid = threadIdx.x;
    const int wid = tid >> 6;
    const int lane = tid & 63;
    const int g = lane >> 4, c = lane & 15;
    const int wv = blockIdx.x * 4 + wid;   // 0..32767
    const int b = wv >> 4, h = wv & 15;
    const int w = b & 63;
    float* psh = p_all[wid];

    const __bf16* base = qkv + (long)b * 49 * 1536;

    bf16x8 zero8;
    for (int i = 0; i < 8; ++i) zero8[i] = (__bf16)0.f;

    // Q fragments (A-layout) and K fragments (B-layout): 16B contiguous per lane
    bf16x8 aq[4], bk[4];
    for (int t4 = 0; t4 < 4; ++t4) {
        int t = t4 * 16 + c;
        const __bf16* p = base + (long)t * 1536 + h * 32 + g * 8;
        bool ok = t < 49;
        aq[t4] = ok ? *(const bf16x8*)p : zero8;
        bk[t4] = ok ? *(const bf16x8*)(p + 512) : zero8;
    }

    // acc init = rel_bias + mask (addm), C-layout: row = g*4+rr (i), col = c (j)
    const float* am = addm + (long)(h * 64 + w) * 64 * 64;
    f32x4 acc[4][4];
    for (int mt = 0; mt < 4; ++mt)
        for (int nt = 0; nt < 4; ++nt) {
            const float4 v = *(const float4*)(am + (long)(nt * 16 + c) * 64 + mt * 16 + g * 4);
            acc[mt][nt] = (f32x4){v.x, v.y, v.z, v.w};
        }

    for (int mt = 0; mt < 4; ++mt)
        for (int nt = 0; nt < 4; ++nt)
            acc[mt][nt] = __builtin_amdgcn_mfma_f32_16x16x32_bf16(aq[mt], bk[nt], acc[mt][nt], 0, 0, 0);

    // row softmax (rows live across 16 lanes with same g; cols across 4 nt tiles)
    float linv[4][4];
    for (int mt = 0; mt < 4; ++mt)
        for (int rr = 0; rr < 4; ++rr) {
            float mx = fmaxf(fmaxf(acc[mt][0][rr], acc[mt][1][rr]),
                             fmaxf(acc[mt][2][rr], acc[mt][3][rr]));
            for (int s = 1; s < 16; s <<= 1) mx = fmaxf(mx, __shfl_xor(mx, s));
            float sum = 0.f;
            for (int nt = 0; nt < 4; ++nt) {
                float p = __expf(acc[mt][nt][rr] - mx);
                acc[mt][nt][rr] = p;
                sum += p;
            }
            for (int s = 1; s < 16; s <<= 1) sum += __shfl_xor(sum, s);
            linv[mt][rr] = 1.0f / sum;
        }

    // P: C-layout -> LDS (f32, row stride 68 words: 16B-aligned rows, spread banks)
    for (int mt = 0; mt < 4; ++mt)
        for (int nt = 0; nt < 4; ++nt)
            for (int rr = 0; rr < 4; ++rr)
                psh[(mt * 16 + g * 4 + rr) * 68 + nt * 16 + c] = acc[mt][nt][rr];
    __syncthreads();

    // V fragments (B-layout): B[k=tok][n=d] gathered as 2B loads
    bf16x8 bv[2][2];
    const __bf16* vbase = base + 1024 + h * 32;
    for (int nt = 0; nt < 2; ++nt)
        for (int k2 = 0; k2 < 2; ++k2) {
            bf16x8 t = zero8;
            int d = nt * 16 + c;
            for (int jj = 0; jj < 8; ++jj) {
                int tok = k2 * 32 + g * 8 + jj;
                if (tok < 49) t[jj] = vbase[(long)tok * 1536 + d];
            }
            bv[nt][k2] = t;
        }

    // P fragments (A-layout) from LDS, cvt f32->bf16
    bf16x8 ap[4][2];
    for (int mt = 0; mt < 4; ++mt)
        for (int k2 = 0; k2 < 2; ++k2) {
            const float* pp = psh + (mt * 16 + c) * 68 + k2 * 32 + g * 8;
            float4 x0 = *(const float4*)pp;
            float4 x1 = *(const float4*)(pp + 4);
            bf16x8 t;
            t[0] = (__bf16)x0.x; t[1] = (__bf16)x0.y; t[2] = (__bf16)x0.z; t[3] = (__bf16)x0.w;
            t[4] = (__bf16)x1.x; t[5] = (__bf16)x1.y; t[6] = (__bf16)x1.z; t[7] = (__bf16)x1.w;
            ap[mt][k2] = t;
        }

    f32x4 oacc[4][2];
    for (int mt = 0; mt < 4; ++mt)
        for (int nt = 0; nt < 2; ++nt) oacc[mt][nt] = (f32x4){0.f, 0.f, 0.f, 0.f};
    for (int mt = 0; mt < 4; ++mt)
        for (int nt = 0; nt < 2; ++nt)
            for (int k2 = 0; k2 < 2; ++k2)
                oacc[mt][nt] = __builtin_amdgcn_mfma_f32_16x16x32_bf16(ap[mt][k2], bv[nt][k2], oacc[mt][nt], 0, 0, 0);

    __bf16* obase = ao + (long)b * 49 * 512 + h * 32;
    for (int mt = 0; mt < 4; ++mt)
        for (int rr = 0; rr < 4; ++rr) {
            int i = mt * 16 + g * 4 + rr;
            if (i < 49) {
                float s = linv[mt][rr];
                for (int nt = 0; nt < 2; ++nt)
                    obase[(long)i * 512 + nt * 16 + c] = (__bf16)(oacc[mt][nt][rr] * s);
            }
        }
}

// ---------------- launch ----------------

extern "C" void kernel_launch(void* const* d_in, const int* in_sizes, int n_in,
                              void* d_out, int out_size, void* d_ws, size_t ws_size,
                              hipStream_t stream) {
    const float* x      = (const float*)d_in[0];
    const float* mask   = (const float*)d_in[1];
    const float* qkv_w  = (const float*)d_in[2];
    const float* qkv_b  = (const float*)d_in[3];
    const float* proj_w = (const float*)d_in[4];
    const float* proj_b = (const float*)d_in[5];
    const float* btab   = (const float*)d_in[6];
    float* out = (float*)d_out;

    char* ws = (char*)d_ws;
    // layout (bytes):
    //   ws_x / ws_ao : 100352*512*2  = 102,760,448   @ 0        (x_bf16, later reused as attn_out)
    //   ws_qkv       : 100352*1536*2 = 308,281,344   @ 102,760,448
    //   wqkv_t       : 1536*512*2    = 1,572,864     @ 411,041,792
    //   wp_t         : 512*512*2     = 524,288       @ 412,614,656
    //   qkvb_s       : 1536*4        = 6,144         @ 413,138,944
    //   addm         : 16*64*64*64*4 = 16,777,216    @ 413,145,088   (end 429,922,304)
    __bf16* ws_x   = (__bf16*)ws;
    __bf16* ws_ao  = (__bf16*)ws;
    __bf16* ws_qkv = (__bf16*)(ws + 102760448L);
    __bf16* wqkv_t = (__bf16*)(ws + 411041792L);
    __bf16* wp_t   = (__bf16*)(ws + 412614656L);
    float*  qkvb_s = (float*)(ws + 413138944L);
    float*  addm   = (float*)(ws + 413145088L);

    const long XN = (long)MTOT * 512;   // 51,380,224

    cvt_x<<<25088, 256, 0, stream>>>(x, ws_x, XN);
    prep_w<<<4102, 256, 0, stream>>>(qkv_w, proj_w, qkv_b, wqkv_t, wp_t, qkvb_s);
    prep_addm<<<16384, 256, 0, stream>>>(mask, btab, addm);

    gemm_k512<1><<<dim3(12, 784), 256, 0, stream>>>(ws_x, wqkv_t, qkvb_s, (void*)ws_qkv, 1536);
    attn_k<<<8192, 256, 0, stream>>>(ws_qkv, addm, ws_ao);
    gemm_k512<0><<<dim3(4, 784), 256, 0, stream>>>(ws_ao, wp_t, proj_b, (void*)out, 512);
}

// Round 2
// 965.661 us; speedup vs baseline: 1.0250x; 1.0250x over previous
//
#include <hip/hip_runtime.h>
#include <cstdint>

#define NTOK  49
#define NHEAD 16
#define HD    32
#define BATCH 2048
#define MTOT  (BATCH*NTOK)                 // 100352
#define SCALE 0.17677669529663687f        // 1/sqrt(32)

typedef float  f32x4  __attribute__((ext_vector_type(4)));
typedef __bf16 bf16x8 __attribute__((ext_vector_type(8)));
typedef __bf16 bf16x4 __attribute__((ext_vector_type(4)));
typedef unsigned int u32;
typedef const u32 __attribute__((address_space(1)))* gas_u32p;
typedef u32 __attribute__((address_space(3)))* las_u32p;

__device__ __forceinline__ void gld16(__bf16* lds, const __bf16* g) {
    __builtin_amdgcn_global_load_lds((gas_u32p)(const void*)g, (las_u32p)(void*)lds, 16, 0, 0);
}

// ---------------- prep kernels ----------------

__global__ __launch_bounds__(256) void cvt_x(const float* __restrict__ x,
                                             __bf16* __restrict__ o, long n) {
    long i = ((long)blockIdx.x * 256 + threadIdx.x) * 8;
    if (i >= n) return;
    float4 a = *(const float4*)(x + i);
    float4 b = *(const float4*)(x + i + 4);
    bf16x8 t;
    t[0] = (__bf16)a.x; t[1] = (__bf16)a.y; t[2] = (__bf16)a.z; t[3] = (__bf16)a.w;
    t[4] = (__bf16)b.x; t[5] = (__bf16)b.y; t[6] = (__bf16)b.z; t[7] = (__bf16)b.w;
    *(bf16x8*)(o + i) = t;
}

__global__ __launch_bounds__(256) void prep_w(const float* __restrict__ qkv_w,
                                              const float* __restrict__ proj_w,
                                              const float* __restrict__ qkv_b,
                                              __bf16* __restrict__ wqkv_t,
                                              __bf16* __restrict__ wp_t,
                                              float* __restrict__ qkvb_s) {
    int idx = blockIdx.x * 256 + threadIdx.x;
    if (idx < 1536 * 512) {
        int nn = idx >> 9, kk = idx & 511;
        float v = qkv_w[kk * 1536 + nn];
        if (nn < 512) v *= SCALE;
        wqkv_t[idx] = (__bf16)v;
    } else if (idx < 1536 * 512 + 512 * 512) {
        int j = idx - 1536 * 512;
        int nn = j >> 9, kk = j & 511;
        wp_t[j] = (__bf16)proj_w[kk * 512 + nn];
    } else if (idx < 1536 * 512 + 512 * 512 + 1536) {
        int n = idx - (1536 * 512 + 512 * 512);
        float v = qkv_b[n];
        if (n < 512) v *= SCALE;
        qkvb_s[n] = v;
    }
}

// addm in per-lane MFMA-fragment order:
// addm[((h*64+w)*16 + mt*4+nt)*256 + lane*4 + rr] = bias+mask for
//   i = mt*16 + (lane>>4)*4 + rr, j = nt*16 + (lane&15)
__global__ __launch_bounds__(256) void prep_addm(const float* __restrict__ mask,
                                                 const float* __restrict__ bias_table,
                                                 float* __restrict__ addm) {
    int idx = blockIdx.x * 256 + threadIdx.x;       // 16*64*16*256 = 4194304 exact
    int rr   = idx & 3;
    int lane = (idx >> 2) & 63;
    int tile = (idx >> 8) & 15;
    int w    = (idx >> 12) & 63;
    int h    = idx >> 18;
    int mt = tile >> 2, nt = tile & 3;
    int g = lane >> 4, c = lane & 15;
    int i = mt * 16 + g * 4 + rr;
    int j = nt * 16 + c;
    float v;
    if (j >= 49)      v = -1e30f;
    else if (i >= 49) v = 0.f;
    else {
        int ai = (i * 37) >> 8, aj = i - ai * 7;
        int bi = (j * 37) >> 8, bj = j - bi * 7;
        int ridx = (ai - bi + 6) * 13 + (aj - bj + 6);
        v = bias_table[ridx * 16 + h] + mask[(w * 49 + i) * 49 + j];
    }
    addm[idx] = v;
}

// ---------------- GEMM (M x 512) * (512 x N) with Bt[N,512], 128x128 tile ----------------
// MODE 0: fp32 out [M,N] + bias
// MODE 1: qkv split — n<1024 -> bf16 qk[b*49+t][1024]; n>=1024 -> bf16 vT[b][h][d][t64]

template <int MODE>
__global__ __launch_bounds__(256)
void gemm_k512(const __bf16* __restrict__ A, const __bf16* __restrict__ Bt,
               const float* __restrict__ bias, float* __restrict__ outF,
               __bf16* __restrict__ outQK, __bf16* __restrict__ outVT, int N) {
    __shared__ __bf16 a_sh[128 * 32];
    __shared__ __bf16 b_sh[128 * 32];
    const int tid = threadIdx.x;
    const int wid = tid >> 6;
    const int lane = tid & 63;
    const int g = lane >> 4, c = lane & 15;
    const int r = lane >> 2;
    const int c8 = (lane & 3) * 8;
    const long m0 = (long)blockIdx.y * 128;
    const long n0 = (long)blockIdx.x * 128;

    const __bf16* aA = A + (m0 + wid * 32 + r) * 512 + c8;
    const __bf16* aB = Bt + (n0 + wid * 32 + r) * 512 + c8;
    __bf16* lA = a_sh + wid * 32 * 32;
    __bf16* lB = b_sh + wid * 32 * 32;

    f32x4 acc[4][4];
    for (int i = 0; i < 4; ++i)
        for (int j = 0; j < 4; ++j) acc[i][j] = (f32x4){0.f, 0.f, 0.f, 0.f};

    const int wm = (wid >> 1) * 64;
    const int wn = (wid & 1) * 64;

    for (int kt = 0; kt < 16; ++kt) {
        const int ko = kt * 32;
        gld16(lA,           aA + ko);
        gld16(lA + 16 * 32, aA + (long)16 * 512 + ko);
        gld16(lB,           aB + ko);
        gld16(lB + 16 * 32, aB + (long)16 * 512 + ko);
        __syncthreads();
        bf16x8 af[4], bf[4];
        for (int mt = 0; mt < 4; ++mt)
            af[mt] = *(const bf16x8*)(a_sh + (wm + mt * 16 + c) * 32 + g * 8);
        for (int nt = 0; nt < 4; ++nt)
            bf[nt] = *(const bf16x8*)(b_sh + (wn + nt * 16 + c) * 32 + g * 8);
        for (int mt = 0; mt < 4; ++mt)
            for (int nt = 0; nt < 4; ++nt)
                acc[mt][nt] = __builtin_amdgcn_mfma_f32_16x16x32_bf16(af[mt], bf[nt], acc[mt][nt], 0, 0, 0);
        __syncthreads();
    }

    for (int nt = 0; nt < 4; ++nt) {
        const long n = n0 + wn + nt * 16 + c;
        const float bv = bias[n];
        for (int mt = 0; mt < 4; ++mt) {
            const long row0 = m0 + wm + mt * 16 + g * 4;
            if (MODE == 0) {
                for (int rr = 0; rr < 4; ++rr)
                    outF[(row0 + rr) * (long)N + n] = acc[mt][nt][rr] + bv;
            } else if (n0 < 1024) {
                for (int rr = 0; rr < 4; ++rr)
                    outQK[(row0 + rr) * 1024 + n] = (__bf16)(acc[mt][nt][rr] + bv);
            } else {
                const int h = ((int)n - 1024) >> 5;
                const int d = ((int)n - 1024) & 31;
                for (int rr = 0; rr < 4; ++rr) {
                    int row = (int)row0 + rr;
                    int b2 = row / 49;
                    int t2 = row - b2 * 49;
                    outVT[(long)(b2 * 512 + h * 32 + d) * 64 + t2] = (__bf16)(acc[mt][nt][rr] + bv);
                }
            }
        }
    }
}

// ---------------- attention: one wave per (b,h), O^T = V^T * P^T ----------------

__global__ __launch_bounds__(256)
void attn_k(const __bf16* __restrict__ qk, const __bf16* __restrict__ vT,
            const float* __restrict__ addm, __bf16* __restrict__ ao) {
    __shared__ __bf16 p_all[4][64 * 72];
    const int tid = threadIdx.x;
    const int wid = tid >> 6;
    const int lane = tid & 63;
    const int g = lane >> 4, c = lane & 15;
    const int wv = blockIdx.x * 4 + wid;   // 0..32767
    const int b = wv >> 4, h = wv & 15;
    const int w = b & 63;
    __bf16* psh = p_all[wid];

    const __bf16* base = qk + (long)b * 49 * 1024 + h * 32;

    bf16x8 zero8;
    for (int i = 0; i < 8; ++i) zero8[i] = (__bf16)0.f;

    // Q (A-layout rows m=t) and K (B-layout cols n=t): 16B contiguous per lane
    bf16x8 aq[4], bk[4];
    for (int t4 = 0; t4 < 4; ++t4) {
        int t = t4 * 16 + c;
        const __bf16* p = base + (long)t * 1024 + g * 8;
        bool ok = t < 49;
        aq[t4] = ok ? *(const bf16x8*)p : zero8;
        bk[t4] = ok ? *(const bf16x8*)(p + 512) : zero8;
    }

    // acc init = rel_bias + mask, fragment-ordered -> fully coalesced float4/lane
    const float* am = addm + (long)(h * 64 + w) * 4096;
    f32x4 acc[4][4];
    for (int mt = 0; mt < 4; ++mt)
        for (int nt = 0; nt < 4; ++nt)
            acc[mt][nt] = *(const f32x4*)(am + (mt * 4 + nt) * 256 + lane * 4);

    for (int mt = 0; mt < 4; ++mt)
        for (int nt = 0; nt < 4; ++nt)
            acc[mt][nt] = __builtin_amdgcn_mfma_f32_16x16x32_bf16(aq[mt], bk[nt], acc[mt][nt], 0, 0, 0);

    // row softmax (row i lives across the 16 lanes sharing g; cols across nt tiles)
    float linv[4][4];
    for (int mt = 0; mt < 4; ++mt)
        for (int rr = 0; rr < 4; ++rr) {
            float mx = fmaxf(fmaxf(acc[mt][0][rr], acc[mt][1][rr]),
                             fmaxf(acc[mt][2][rr], acc[mt][3][rr]));
            for (int s = 1; s < 16; s <<= 1) mx = fmaxf(mx, __shfl_xor(mx, s));
            float sum = 0.f;
            for (int nt = 0; nt < 4; ++nt) {
                float p = __expf(acc[mt][nt][rr] - mx);
                acc[mt][nt][rr] = p;
                sum += p;
            }
            for (int s = 1; s < 16; s <<= 1) sum += __shfl_xor(sum, s);
            linv[mt][rr] = 1.0f / sum;
        }

    // normalized P (bf16) -> wave-private LDS [i][t], stride 72; no barrier needed
    for (int mt = 0; mt < 4; ++mt)
        for (int nt = 0; nt < 4; ++nt)
            for (int rr = 0; rr < 4; ++rr)
                psh[(mt * 16 + g * 4 + rr) * 72 + nt * 16 + c] =
                    (__bf16)(acc[mt][nt][rr] * linv[mt][rr]);

    // V^T fragments (A-layout, m=d): clean 16B global loads from vT
    const __bf16* vb = vT + (long)(b * 16 + h) * 2048;   // 32*64
    bf16x8 av[2][2];
    for (int mt2 = 0; mt2 < 2; ++mt2)
        for (int k2 = 0; k2 < 2; ++k2)
            av[mt2][k2] = *(const bf16x8*)(vb + (mt2 * 16 + c) * 64 + k2 * 32 + g * 8);

    // P^T fragments (B-layout, n=i): contiguous b128 reads of P rows
    bf16x8 bp[4][2];
    for (int nt2 = 0; nt2 < 4; ++nt2)
        for (int k2 = 0; k2 < 2; ++k2)
            bp[nt2][k2] = *(const bf16x8*)(psh + (nt2 * 16 + c) * 72 + k2 * 32 + g * 8);

    f32x4 oacc[2][4];
    for (int mt2 = 0; mt2 < 2; ++mt2)
        for (int nt2 = 0; nt2 < 4; ++nt2) oacc[mt2][nt2] = (f32x4){0.f, 0.f, 0.f, 0.f};
    for (int mt2 = 0; mt2 < 2; ++mt2)
        for (int nt2 = 0; nt2 < 4; ++nt2)
            for (int k2 = 0; k2 < 2; ++k2)
                oacc[mt2][nt2] = __builtin_amdgcn_mfma_f32_16x16x32_bf16(av[mt2][k2], bp[nt2][k2], oacc[mt2][nt2], 0, 0, 0);

    // O^T C-layout: col = i = nt2*16+c, row = d = mt2*16+g*4+rr -> 8B packed stores
    __bf16* obase = ao + (long)b * 49 * 512 + h * 32;
    for (int nt2 = 0; nt2 < 4; ++nt2) {
        int i = nt2 * 16 + c;
        if (i < 49) {
            for (int mt2 = 0; mt2 < 2; ++mt2) {
                bf16x4 t;
                t[0] = (__bf16)oacc[mt2][nt2][0];
                t[1] = (__bf16)oacc[mt2][nt2][1];
                t[2] = (__bf16)oacc[mt2][nt2][2];
                t[3] = (__bf16)oacc[mt2][nt2][3];
                *(bf16x4*)(obase + (long)i * 512 + mt2 * 16 + g * 4) = t;
            }
        }
    }
}

// ---------------- launch ----------------

extern "C" void kernel_launch(void* const* d_in, const int* in_sizes, int n_in,
                              void* d_out, int out_size, void* d_ws, size_t ws_size,
                              hipStream_t stream) {
    const float* x      = (const float*)d_in[0];
    const float* mask   = (const float*)d_in[1];
    const float* qkv_w  = (const float*)d_in[2];
    const float* qkv_b  = (const float*)d_in[3];
    const float* proj_w = (const float*)d_in[4];
    const float* proj_b = (const float*)d_in[5];
    const float* btab   = (const float*)d_in[6];
    float* out = (float*)d_out;

    char* ws = (char*)d_ws;
    // layout (bytes):
    //   ws_x / ws_ao : 100352*512*2     = 102,760,448  @ 0
    //   ws_qk        : 100352*1024*2    = 205,520,896  @ 102,760,448
    //   wqkv_t       : 1536*512*2       = 1,572,864    @ 308,281,344
    //   wp_t         : 512*512*2        = 524,288      @ 309,854,208
    //   qkvb_s       : 1536*4           = 6,144        @ 310,378,496
    //   addm         : 16*64*16*256*4   = 16,777,216   @ 310,384,640
    //   vT           : 32768*32*64*2    = 134,217,728  @ 327,161,856  (end 461,379,584)
    __bf16* ws_x   = (__bf16*)ws;
    __bf16* ws_ao  = (__bf16*)ws;
    __bf16* ws_qk  = (__bf16*)(ws + 102760448L);
    __bf16* wqkv_t = (__bf16*)(ws + 308281344L);
    __bf16* wp_t   = (__bf16*)(ws + 309854208L);
    float*  qkvb_s = (float*)(ws + 310378496L);
    float*  addm   = (float*)(ws + 310384640L);
    __bf16* ws_vT  = (__bf16*)(ws + 327161856L);

    const long XN = (long)MTOT * 512;   // 51,380,224

    cvt_x<<<25088, 256, 0, stream>>>(x, ws_x, XN);
    prep_w<<<4102, 256, 0, stream>>>(qkv_w, proj_w, qkv_b, wqkv_t, wp_t, qkvb_s);
    prep_addm<<<16384, 256, 0, stream>>>(mask, btab, addm);

    gemm_k512<1><<<dim3(12, 784), 256, 0, stream>>>(ws_x, wqkv_t, qkvb_s, nullptr, ws_qk, ws_vT, 1536);
    attn_k<<<8192, 256, 0, stream>>>(ws_qk, ws_vT, addm, ws_ao);
    gemm_k512<0><<<dim3(4, 784), 256, 0, stream>>>(ws_ao, wp_t, proj_b, out, nullptr, nullptr, 512);
}